// Round 7
// baseline (257.649 us; speedup 1.0000x reference)
//
#include <hip/hip_runtime.h>
#include <hip/hip_bf16.h>

typedef __attribute__((ext_vector_type(8))) short short8;
typedef __attribute__((ext_vector_type(4))) float f32x4;
typedef unsigned short u16;

#define NEGINF (-1e9f)

__device__ __forceinline__ u16 f2bf(float x) {
    union { float f; unsigned int u; } v; v.f = x;
    unsigned int r = v.u + 0x7fff + ((v.u >> 16) & 1);
    return (u16)(r >> 16);
}

__device__ __forceinline__ void gload16(const void* g, void* l) {
    __builtin_amdgcn_global_load_lds(
        (const __attribute__((address_space(1))) unsigned int*)g,
        (__attribute__((address_space(3))) unsigned int*)l, 16, 0, 0);
}

// ---------------- cast hidden fp32 -> bf16 ----------------
__global__ __launch_bounds__(256) void cast_hidden_kernel(const float* __restrict__ in,
                                                          u16* __restrict__ out) {
    int idx = (blockIdx.x * 256 + threadIdx.x) * 4;
    float4 v = *(const float4*)&in[idx];
    ushort4 o;
    o.x = f2bf(v.x); o.y = f2bf(v.y); o.z = f2bf(v.z); o.w = f2bf(v.w);
    *(ushort4*)&out[idx] = o;
}

// ---------------- weight prep: w = pw * (rm^T sm) + (r^T s), bf16 out ----------------
__global__ __launch_bounds__(256) void prep_w_kernel(const float* __restrict__ w,
                                                     const float* __restrict__ rm,
                                                     const float* __restrict__ sm,
                                                     const float* __restrict__ ra,
                                                     const float* __restrict__ sa,
                                                     const int* __restrict__ lang,
                                                     u16* __restrict__ out, int rows) {
    const int li = lang[0];
    int idx = blockIdx.x * 256 + threadIdx.x;
    int e = idx >> 8;
    int f = (idx & 255) * 4;
    float4 pw = *(const float4*)&w[(size_t)e * 1024 + f];
    float mul0 = 0.f, mul1 = 0.f, mul2 = 0.f, mul3 = 0.f;
    float add0 = 0.f, add1 = 0.f, add2 = 0.f, add3 = 0.f;
#pragma unroll
    for (int r = 0; r < 4; r++) {
        float a = rm[(size_t)(li * 4 + r) * rows + e];
        float4 b = *(const float4*)&sm[(size_t)(li * 4 + r) * 1024 + f];
        float c = ra[(size_t)(li * 4 + r) * rows + e];
        float4 d = *(const float4*)&sa[(size_t)(li * 4 + r) * 1024 + f];
        mul0 += a * b.x; mul1 += a * b.y; mul2 += a * b.z; mul3 += a * b.w;
        add0 += c * d.x; add1 += c * d.y; add2 += c * d.z; add3 += c * d.w;
    }
    ushort4 o;
    o.x = f2bf(pw.x * mul0 + add0);
    o.y = f2bf(pw.y * mul1 + add1);
    o.z = f2bf(pw.z * mul2 + add2);
    o.w = f2bf(pw.w * mul3 + add3);
    *(ushort4*)&out[(size_t)e * 1024 + f] = o;
}

// ---------------- 128x128 bf16 MFMA GEMM, A:MxK row-major, W:NxK row-major ----------------
// EPI 0: qkv epilogue (q scaled by SCALE*log2e; q,k,v all row-major coalesced).
// EPI 1: fp32 out + bias.
template <int EPI>
__global__ __launch_bounds__(256) void gemm_bf16(const u16* __restrict__ A,
                                                 const u16* __restrict__ W,
                                                 const float* __restrict__ bias,
                                                 int K,
                                                 float* __restrict__ outF,
                                                 u16* __restrict__ qb,
                                                 u16* __restrict__ kb,
                                                 u16* __restrict__ vb) {
    __shared__ __align__(16) u16 As[128 * 32];
    __shared__ __align__(16) u16 Bs[128 * 32];
    const int t = threadIdx.x;
    const int lane = t & 63, wv = t >> 6;
    const int lr = lane & 15, lk = lane >> 4;
    const int wr = wv >> 1, wc = wv & 1;
    const int m0 = blockIdx.y * 128, n0 = blockIdx.x * 128;

    const int rowS = t >> 2, kcS = t & 3;
    const u16* gA0 = A + (size_t)(m0 + rowS) * K + kcS * 8;
    const u16* gA1 = gA0 + (size_t)64 * K;
    const u16* gB0 = W + (size_t)(n0 + rowS) * K + kcS * 8;
    const u16* gB1 = gB0 + (size_t)64 * K;
    char* ldsA0 = (char*)As + wv * 1024;
    char* ldsA1 = (char*)As + 4096 + wv * 1024;
    char* ldsB0 = (char*)Bs + wv * 1024;
    char* ldsB1 = (char*)Bs + 4096 + wv * 1024;

    f32x4 acc[4][4] = {};

    for (int k0 = 0; k0 < K; k0 += 32) {
        gload16(gA0 + k0, ldsA0);
        gload16(gA1 + k0, ldsA1);
        gload16(gB0 + k0, ldsB0);
        gload16(gB1 + k0, ldsB1);
        __syncthreads();
        short8 af[4], bf[4];
#pragma unroll
        for (int mi = 0; mi < 4; mi++)
            af[mi] = *(const short8*)&As[(wr * 64 + mi * 16 + lr) * 32 + lk * 8];
#pragma unroll
        for (int ni = 0; ni < 4; ni++)
            bf[ni] = *(const short8*)&Bs[(wc * 64 + ni * 16 + lr) * 32 + lk * 8];
#pragma unroll
        for (int mi = 0; mi < 4; mi++)
#pragma unroll
            for (int ni = 0; ni < 4; ni++)
                acc[mi][ni] = __builtin_amdgcn_mfma_f32_16x16x32_bf16(af[mi], bf[ni], acc[mi][ni], 0, 0, 0);
        __syncthreads();
    }

#pragma unroll
    for (int mi = 0; mi < 4; mi++) {
#pragma unroll
        for (int ni = 0; ni < 4; ni++) {
            int n = n0 + wc * 64 + ni * 16 + lr;
            float bv = bias[n];
#pragma unroll
            for (int i = 0; i < 4; i++) {
                int m = m0 + wr * 64 + mi * 16 + lk * 4 + i;
                float val = acc[mi][ni][i] + bv;
                if (EPI == 0) {
                    int tt = m >> 1, bb = m & 1;
                    int h = n / 192;
                    int rem = n - h * 192;
                    int s = rem >> 6, d = rem & 63;
                    size_t bh = (size_t)(bb * 16 + h);
                    // q pre-scaled by SCALE*log2(e) so attn can use exp2
                    if (s == 0)      qb[(bh * 2048 + tt) * 64 + d] = f2bf(val * 0.18033688f);
                    else if (s == 1) kb[(bh * 2048 + tt) * 64 + d] = f2bf(val);
                    else             vb[(bh * 2048 + tt) * 64 + d] = f2bf(val);
                } else {
                    outF[(size_t)m * 1024 + n] = val;
                }
            }
        }
    }
}

// ---------------- V transpose: vb (BH,T,64) -> vtb (BH,64,T), coalesced both sides ----
__global__ __launch_bounds__(256) void tr_v_kernel(const u16* __restrict__ vb,
                                                   u16* __restrict__ vtb) {
    __shared__ u16 tile[64][72];
    const int bh = blockIdx.y;
    const int t0 = blockIdx.x * 64;
    const int tid = threadIdx.x;
    const int row = tid >> 3, c8 = (tid & 7) * 8;
#pragma unroll
    for (int p = 0; p < 2; p++) {
        short8 v = *(const short8*)&vb[((size_t)bh * 2048 + t0 + row + p * 32) * 64 + c8];
        *(short8*)&tile[row + p * 32][c8] = v;
    }
    __syncthreads();
    const int d = tid >> 2, tg = (tid & 3) * 16;
    short8 a, b;
#pragma unroll
    for (int j = 0; j < 8; j++) a[j] = tile[tg + j][d];
#pragma unroll
    for (int j = 0; j < 8; j++) b[j] = tile[tg + 8 + j][d];
    *(short8*)&vtb[((size_t)bh * 64 + d) * 2048 + t0 + tg] = a;
    *(short8*)&vtb[((size_t)bh * 64 + d) * 2048 + t0 + tg + 8] = b;
}

// ---------------- causal flash attention (LDS-staged, paired strips, exp2) ----------
// q: (BH, T, 64) bf16 scaled by SCALE*log2e; k: (BH, T, 64) bf16; vt: (BH, 64, T) bf16
// ctx out: (T*B, 1024) bf16
// Grid: 512 blocks linear. Block handles strips {pair, 31-pair} of 64 q-rows each.
__global__ __launch_bounds__(256) void attn_kernel(const u16* __restrict__ qb,
                                                   const u16* __restrict__ kb,
                                                   const u16* __restrict__ vtb,
                                                   u16* __restrict__ ctx) {
    __shared__ __align__(16) u16 Ks[2][4096];
    __shared__ __align__(16) u16 Vs[2][4096];
    __shared__ __align__(16) u16 Plds[4][16][72];

    const int t = threadIdx.x;
    const int lane = t & 63, wv = t >> 6;
    const int lr = lane & 15, lk = lane >> 4;

    const int d = blockIdx.x;
    const int bh = (d & 7) * 4 + ((d >> 3) >> 4);
    const int pair = (d >> 3) & 15;

    const u16* Kg = kb + (size_t)bh * 2048 * 64;
    const u16* Vg = vtb + (size_t)bh * 64 * 2048;
    const int bb = bh >> 4, h = bh & 15;

    const int p0 = wv * 64 + lane;
    const int r0 = p0 >> 3, c0 = (p0 & 7) ^ (r0 & 7);
    const int p1 = 256 + p0;
    const int r1 = p1 >> 3, c1 = (p1 & 7) ^ (r1 & 7);
    const int ldsOff0 = (wv * 64) * 8;
    const int ldsOff1 = (256 + wv * 64) * 8;

#pragma unroll 1
    for (int sidx = 0; sidx < 2; sidx++) {
        const int strip = sidx == 0 ? pair : 31 - pair;
        const int q0 = strip * 64 + wv * 16;
        const u16* Qp = qb + ((size_t)bh * 2048 + q0) * 64;
        short8 qf0 = *(const short8*)&Qp[lr * 64 + lk * 8];
        short8 qf1 = *(const short8*)&Qp[lr * 64 + 32 + lk * 8];

        f32x4 acc[4] = {};
        float mrow[4], ssum[4];
#pragma unroll
        for (int i = 0; i < 4; i++) { mrow[i] = -3e38f; ssum[i] = 0.f; }

        const int nt = strip + 1;
        int buf = 0;

        {
            gload16(Kg + (size_t)(0 + r0) * 64 + c0 * 8, &Ks[0][ldsOff0]);
            gload16(Kg + (size_t)(0 + r1) * 64 + c1 * 8, &Ks[0][ldsOff1]);
            gload16(Vg + (size_t)r0 * 2048 + 0 + c0 * 8, &Vs[0][ldsOff0]);
            gload16(Vg + (size_t)r1 * 2048 + 0 + c1 * 8, &Vs[0][ldsOff1]);
        }
        asm volatile("s_waitcnt vmcnt(0)" ::: "memory");
        __syncthreads();

#pragma unroll 1
        for (int tt = 0; tt < nt; tt++) {
            const int kv0 = tt * 64;
            if (tt + 1 < nt) {
                const int nkv = kv0 + 64;
                gload16(Kg + (size_t)(nkv + r0) * 64 + c0 * 8, &Ks[buf ^ 1][ldsOff0]);
                gload16(Kg + (size_t)(nkv + r1) * 64 + c1 * 8, &Ks[buf ^ 1][ldsOff1]);
                gload16(Vg + (size_t)r0 * 2048 + nkv + c0 * 8, &Vs[buf ^ 1][ldsOff0]);
                gload16(Vg + (size_t)r1 * 2048 + nkv + c1 * 8, &Vs[buf ^ 1][ldsOff1]);
            }

            // ---- QK^T ----
            f32x4 sb[4];
#pragma unroll
            for (int nj = 0; nj < 4; nj++) {
                const int r = nj * 16 + lr;
                short8 kf0 = *(const short8*)&Ks[buf][r * 64 + ((lk    ) ^ (r & 7)) * 8];
                short8 kf1 = *(const short8*)&Ks[buf][r * 64 + ((lk + 4) ^ (r & 7)) * 8];
                f32x4 z = {0.f, 0.f, 0.f, 0.f};
                z = __builtin_amdgcn_mfma_f32_16x16x32_bf16(qf0, kf0, z, 0, 0, 0);
                z = __builtin_amdgcn_mfma_f32_16x16x32_bf16(qf1, kf1, z, 0, 0, 0);
                sb[nj] = z;
            }
            if (kv0 + 63 > q0) {
#pragma unroll
                for (int nj = 0; nj < 4; nj++) {
                    int kv = kv0 + nj * 16 + lr;
#pragma unroll
                    for (int i = 0; i < 4; i++) {
                        int qr = q0 + lk * 4 + i;
                        if (kv > qr) sb[nj][i] = NEGINF;
                    }
                }
            }
            // ---- online softmax (base-2) ----
            float scale[4];
#pragma unroll
            for (int i = 0; i < 4; i++) {
                float mx = fmaxf(fmaxf(sb[0][i], sb[1][i]), fmaxf(sb[2][i], sb[3][i]));
                mx = fmaxf(mx, __shfl_xor(mx, 1, 16));
                mx = fmaxf(mx, __shfl_xor(mx, 2, 16));
                mx = fmaxf(mx, __shfl_xor(mx, 4, 16));
                mx = fmaxf(mx, __shfl_xor(mx, 8, 16));
                float mnew = fmaxf(mrow[i], mx);
                scale[i] = exp2f(mrow[i] - mnew);
                mrow[i] = mnew;
                float psum = 0.f;
#pragma unroll
                for (int nj = 0; nj < 4; nj++) {
                    float p = exp2f(sb[nj][i] - mnew);
                    sb[nj][i] = p;
                    psum += p;
                }
                psum += __shfl_xor(psum, 1, 16);
                psum += __shfl_xor(psum, 2, 16);
                psum += __shfl_xor(psum, 4, 16);
                psum += __shfl_xor(psum, 8, 16);
                ssum[i] = ssum[i] * scale[i] + psum;
            }
#pragma unroll
            for (int nj = 0; nj < 4; nj++)
#pragma unroll
                for (int i = 0; i < 4; i++)
                    Plds[wv][lk * 4 + i][nj * 16 + lr] = f2bf(sb[nj][i]);
#pragma unroll
            for (int ni = 0; ni < 4; ni++)
#pragma unroll
                for (int i = 0; i < 4; i++)
                    acc[ni][i] *= scale[i];
            short8 pf0 = *(const short8*)&Plds[wv][lr][lk * 8];
            short8 pf1 = *(const short8*)&Plds[wv][lr][32 + lk * 8];
            // ---- PV ----
#pragma unroll
            for (int ni = 0; ni < 4; ni++) {
                const int r = ni * 16 + lr;
                short8 vf0 = *(const short8*)&Vs[buf][r * 64 + ((lk    ) ^ (r & 7)) * 8];
                short8 vf1 = *(const short8*)&Vs[buf][r * 64 + ((lk + 4) ^ (r & 7)) * 8];
                acc[ni] = __builtin_amdgcn_mfma_f32_16x16x32_bf16(pf0, vf0, acc[ni], 0, 0, 0);
                acc[ni] = __builtin_amdgcn_mfma_f32_16x16x32_bf16(pf1, vf1, acc[ni], 0, 0, 0);
            }

            asm volatile("s_waitcnt vmcnt(0)" ::: "memory");
            __syncthreads();
            buf ^= 1;
        }

#pragma unroll
        for (int ni = 0; ni < 4; ni++) {
#pragma unroll
            for (int i = 0; i < 4; i++) {
                int tq = q0 + lk * 4 + i;
                float val = acc[ni][i] / ssum[i];
                ctx[(size_t)(tq * 2 + bb) * 1024 + h * 64 + ni * 16 + lr] = f2bf(val);
            }
        }
        __syncthreads();
    }
}

extern "C" void kernel_launch(void* const* d_in, const int* in_sizes, int n_in,
                              void* d_out, int out_size, void* d_ws, size_t ws_size,
                              hipStream_t stream) {
    const float* hs     = (const float*)d_in[0];
    const float* proj_w = (const float*)d_in[1];
    const float* proj_b = (const float*)d_in[2];
    const float* out_w  = (const float*)d_in[3];
    const float* out_b  = (const float*)d_in[4];
    const float* rm_i   = (const float*)d_in[5];
    const float* sm_i   = (const float*)d_in[6];
    const float* rm_o   = (const float*)d_in[7];
    const float* sm_o   = (const float*)d_in[8];
    const float* r_i    = (const float*)d_in[9];
    const float* s_i    = (const float*)d_in[10];
    const float* r_o    = (const float*)d_in[11];
    const float* s_o    = (const float*)d_in[12];
    const int*   lang   = (const int*)d_in[13];
    float* out = (float*)d_out;

    char* ws = (char*)d_ws;
    u16* hsb   = (u16*)(ws);
    u16* w_in  = (u16*)(ws + (size_t)(8 << 20));
    u16* w_out = (u16*)(ws + (size_t)(14 << 20));
    u16* qb    = (u16*)(ws + (size_t)(16 << 20));
    u16* kb    = (u16*)(ws + (size_t)(24 << 20));
    u16* vtb   = (u16*)(ws + (size_t)(32 << 20));
    u16* ctxb  = (u16*)(ws + (size_t)(40 << 20));
    u16* vb    = ctxb;  // vb dead before attn writes ctxb — safe overlap

    cast_hidden_kernel<<<dim3(4096), dim3(256), 0, stream>>>(hs, hsb);
    prep_w_kernel<<<dim3(3072), dim3(256), 0, stream>>>(proj_w, rm_i, sm_i, r_i, s_i, lang, w_in, 3072);
    prep_w_kernel<<<dim3(1024), dim3(256), 0, stream>>>(out_w, rm_o, sm_o, r_o, s_o, lang, w_out, 1024);
    gemm_bf16<0><<<dim3(24, 32), dim3(256), 0, stream>>>(hsb, w_in, proj_b, 1024, (float*)nullptr, qb, kb, vb);
    tr_v_kernel<<<dim3(32, 32), dim3(256), 0, stream>>>(vb, vtb);
    attn_kernel<<<dim3(512), dim3(256), 0, stream>>>(qb, kb, vtb, ctxb);
    gemm_bf16<1><<<dim3(8, 32), dim3(256), 0, stream>>>(ctxb, w_out, out_b, 1024, out, (u16*)nullptr, (u16*)nullptr, (u16*)nullptr);
}

// Round 8
// 252.706 us; speedup vs baseline: 1.0196x; 1.0196x over previous
//
#include <hip/hip_runtime.h>
#include <hip/hip_bf16.h>

typedef __attribute__((ext_vector_type(8))) short short8;
typedef __attribute__((ext_vector_type(4))) float f32x4;
typedef unsigned short u16;

#define NEGINF (-1e9f)

__device__ __forceinline__ u16 f2bf(float x) {
    union { float f; unsigned int u; } v; v.f = x;
    unsigned int r = v.u + 0x7fff + ((v.u >> 16) & 1);
    return (u16)(r >> 16);
}

// raw v_exp_f32: D = 2^x, single transcendental instruction
__device__ __forceinline__ float fast_exp2(float x) {
    float r;
    asm volatile("v_exp_f32 %0, %1" : "=v"(r) : "v"(x));
    return r;
}

__device__ __forceinline__ void gload16(const void* g, void* l) {
    __builtin_amdgcn_global_load_lds(
        (const __attribute__((address_space(1))) unsigned int*)g,
        (__attribute__((address_space(3))) unsigned int*)l, 16, 0, 0);
}

// ---------------- cast hidden fp32 -> bf16 ----------------
__global__ __launch_bounds__(256) void cast_hidden_kernel(const float* __restrict__ in,
                                                          u16* __restrict__ out) {
    int idx = (blockIdx.x * 256 + threadIdx.x) * 4;
    float4 v = *(const float4*)&in[idx];
    ushort4 o;
    o.x = f2bf(v.x); o.y = f2bf(v.y); o.z = f2bf(v.z); o.w = f2bf(v.w);
    *(ushort4*)&out[idx] = o;
}

// ---------------- weight prep: w = pw * (rm^T sm) + (r^T s), bf16 out ----------------
__global__ __launch_bounds__(256) void prep_w_kernel(const float* __restrict__ w,
                                                     const float* __restrict__ rm,
                                                     const float* __restrict__ sm,
                                                     const float* __restrict__ ra,
                                                     const float* __restrict__ sa,
                                                     const int* __restrict__ lang,
                                                     u16* __restrict__ out, int rows) {
    const int li = lang[0];
    int idx = blockIdx.x * 256 + threadIdx.x;
    int e = idx >> 8;
    int f = (idx & 255) * 4;
    float4 pw = *(const float4*)&w[(size_t)e * 1024 + f];
    float mul0 = 0.f, mul1 = 0.f, mul2 = 0.f, mul3 = 0.f;
    float add0 = 0.f, add1 = 0.f, add2 = 0.f, add3 = 0.f;
#pragma unroll
    for (int r = 0; r < 4; r++) {
        float a = rm[(size_t)(li * 4 + r) * rows + e];
        float4 b = *(const float4*)&sm[(size_t)(li * 4 + r) * 1024 + f];
        float c = ra[(size_t)(li * 4 + r) * rows + e];
        float4 d = *(const float4*)&sa[(size_t)(li * 4 + r) * 1024 + f];
        mul0 += a * b.x; mul1 += a * b.y; mul2 += a * b.z; mul3 += a * b.w;
        add0 += c * d.x; add1 += c * d.y; add2 += c * d.z; add3 += c * d.w;
    }
    ushort4 o;
    o.x = f2bf(pw.x * mul0 + add0);
    o.y = f2bf(pw.y * mul1 + add1);
    o.z = f2bf(pw.z * mul2 + add2);
    o.w = f2bf(pw.w * mul3 + add3);
    *(ushort4*)&out[(size_t)e * 1024 + f] = o;
}

// ---------------- 128x128 bf16 MFMA GEMM, A:MxK row-major, W:NxK row-major ----------------
// EPI 0: qkv epilogue (q scaled by SCALE*log2e; q,k,v all row-major coalesced).
// EPI 1: fp32 out + bias.
template <int EPI>
__global__ __launch_bounds__(256) void gemm_bf16(const u16* __restrict__ A,
                                                 const u16* __restrict__ W,
                                                 const float* __restrict__ bias,
                                                 int K,
                                                 float* __restrict__ outF,
                                                 u16* __restrict__ qb,
                                                 u16* __restrict__ kb,
                                                 u16* __restrict__ vb) {
    __shared__ __align__(16) u16 As[128 * 32];
    __shared__ __align__(16) u16 Bs[128 * 32];
    const int t = threadIdx.x;
    const int lane = t & 63, wv = t >> 6;
    const int lr = lane & 15, lk = lane >> 4;
    const int wr = wv >> 1, wc = wv & 1;
    const int m0 = blockIdx.y * 128, n0 = blockIdx.x * 128;

    const int rowS = t >> 2, kcS = t & 3;
    const u16* gA0 = A + (size_t)(m0 + rowS) * K + kcS * 8;
    const u16* gA1 = gA0 + (size_t)64 * K;
    const u16* gB0 = W + (size_t)(n0 + rowS) * K + kcS * 8;
    const u16* gB1 = gB0 + (size_t)64 * K;
    char* ldsA0 = (char*)As + wv * 1024;
    char* ldsA1 = (char*)As + 4096 + wv * 1024;
    char* ldsB0 = (char*)Bs + wv * 1024;
    char* ldsB1 = (char*)Bs + 4096 + wv * 1024;

    f32x4 acc[4][4] = {};

    for (int k0 = 0; k0 < K; k0 += 32) {
        gload16(gA0 + k0, ldsA0);
        gload16(gA1 + k0, ldsA1);
        gload16(gB0 + k0, ldsB0);
        gload16(gB1 + k0, ldsB1);
        __syncthreads();
        short8 af[4], bf[4];
#pragma unroll
        for (int mi = 0; mi < 4; mi++)
            af[mi] = *(const short8*)&As[(wr * 64 + mi * 16 + lr) * 32 + lk * 8];
#pragma unroll
        for (int ni = 0; ni < 4; ni++)
            bf[ni] = *(const short8*)&Bs[(wc * 64 + ni * 16 + lr) * 32 + lk * 8];
#pragma unroll
        for (int mi = 0; mi < 4; mi++)
#pragma unroll
            for (int ni = 0; ni < 4; ni++)
                acc[mi][ni] = __builtin_amdgcn_mfma_f32_16x16x32_bf16(af[mi], bf[ni], acc[mi][ni], 0, 0, 0);
        __syncthreads();
    }

#pragma unroll
    for (int mi = 0; mi < 4; mi++) {
#pragma unroll
        for (int ni = 0; ni < 4; ni++) {
            int n = n0 + wc * 64 + ni * 16 + lr;
            float bv = bias[n];
#pragma unroll
            for (int i = 0; i < 4; i++) {
                int m = m0 + wr * 64 + mi * 16 + lk * 4 + i;
                float val = acc[mi][ni][i] + bv;
                if (EPI == 0) {
                    int tt = m >> 1, bb = m & 1;
                    int h = n / 192;
                    int rem = n - h * 192;
                    int s = rem >> 6, d = rem & 63;
                    size_t bh = (size_t)(bb * 16 + h);
                    // q pre-scaled by SCALE*log2(e) so attn can use exp2
                    if (s == 0)      qb[(bh * 2048 + tt) * 64 + d] = f2bf(val * 0.18033688f);
                    else if (s == 1) kb[(bh * 2048 + tt) * 64 + d] = f2bf(val);
                    else             vb[(bh * 2048 + tt) * 64 + d] = f2bf(val);
                } else {
                    outF[(size_t)m * 1024 + n] = val;
                }
            }
        }
    }
}

// ---------------- V transpose: vb (BH,T,64) -> vtb (BH,64,T), coalesced both sides ----
__global__ __launch_bounds__(256) void tr_v_kernel(const u16* __restrict__ vb,
                                                   u16* __restrict__ vtb) {
    __shared__ u16 tile[64][72];
    const int bh = blockIdx.y;
    const int t0 = blockIdx.x * 64;
    const int tid = threadIdx.x;
    const int row = tid >> 3, c8 = (tid & 7) * 8;
#pragma unroll
    for (int p = 0; p < 2; p++) {
        short8 v = *(const short8*)&vb[((size_t)bh * 2048 + t0 + row + p * 32) * 64 + c8];
        *(short8*)&tile[row + p * 32][c8] = v;
    }
    __syncthreads();
    const int d = tid >> 2, tg = (tid & 3) * 16;
    short8 a, b;
#pragma unroll
    for (int j = 0; j < 8; j++) a[j] = tile[tg + j][d];
#pragma unroll
    for (int j = 0; j < 8; j++) b[j] = tile[tg + 8 + j][d];
    *(short8*)&vtb[((size_t)bh * 64 + d) * 2048 + t0 + tg] = a;
    *(short8*)&vtb[((size_t)bh * 64 + d) * 2048 + t0 + tg + 8] = b;
}

// ---------------- causal flash attention (LDS-staged, paired strips, v_exp_f32) ------
// q: (BH, T, 64) bf16 scaled by SCALE*log2e; k: (BH, T, 64) bf16; vt: (BH, 64, T) bf16
// ctx out: (T*B, 1024) bf16
// Grid: 512 blocks linear. Block handles strips {pair, 31-pair} of 64 q-rows each.
__global__ __launch_bounds__(256) void attn_kernel(const u16* __restrict__ qb,
                                                   const u16* __restrict__ kb,
                                                   const u16* __restrict__ vtb,
                                                   u16* __restrict__ ctx) {
    __shared__ __align__(16) u16 Ks[2][4096];
    __shared__ __align__(16) u16 Vs[2][4096];
    __shared__ __align__(16) u16 Plds[4][16][72];

    const int t = threadIdx.x;
    const int lane = t & 63, wv = t >> 6;
    const int lr = lane & 15, lk = lane >> 4;

    const int d = blockIdx.x;
    const int bh = (d & 7) * 4 + ((d >> 3) >> 4);
    const int pair = (d >> 3) & 15;

    const u16* Kg = kb + (size_t)bh * 2048 * 64;
    const u16* Vg = vtb + (size_t)bh * 64 * 2048;
    const int bb = bh >> 4, h = bh & 15;

    const int p0 = wv * 64 + lane;
    const int r0 = p0 >> 3, c0 = (p0 & 7) ^ (r0 & 7);
    const int p1 = 256 + p0;
    const int r1 = p1 >> 3, c1 = (p1 & 7) ^ (r1 & 7);
    const int ldsOff0 = (wv * 64) * 8;
    const int ldsOff1 = (256 + wv * 64) * 8;

#pragma unroll 1
    for (int sidx = 0; sidx < 2; sidx++) {
        const int strip = sidx == 0 ? pair : 31 - pair;
        const int q0 = strip * 64 + wv * 16;
        const u16* Qp = qb + ((size_t)bh * 2048 + q0) * 64;
        short8 qf0 = *(const short8*)&Qp[lr * 64 + lk * 8];
        short8 qf1 = *(const short8*)&Qp[lr * 64 + 32 + lk * 8];

        f32x4 acc[4] = {};
        float mrow[4], ssum[4];
#pragma unroll
        for (int i = 0; i < 4; i++) { mrow[i] = -3e38f; ssum[i] = 0.f; }

        const int nt = strip + 1;
        int buf = 0;

        {
            gload16(Kg + (size_t)(0 + r0) * 64 + c0 * 8, &Ks[0][ldsOff0]);
            gload16(Kg + (size_t)(0 + r1) * 64 + c1 * 8, &Ks[0][ldsOff1]);
            gload16(Vg + (size_t)r0 * 2048 + 0 + c0 * 8, &Vs[0][ldsOff0]);
            gload16(Vg + (size_t)r1 * 2048 + 0 + c1 * 8, &Vs[0][ldsOff1]);
        }
        asm volatile("s_waitcnt vmcnt(0)" ::: "memory");
        __syncthreads();

#pragma unroll 1
        for (int tt = 0; tt < nt; tt++) {
            const int kv0 = tt * 64;
            if (tt + 1 < nt) {
                const int nkv = kv0 + 64;
                gload16(Kg + (size_t)(nkv + r0) * 64 + c0 * 8, &Ks[buf ^ 1][ldsOff0]);
                gload16(Kg + (size_t)(nkv + r1) * 64 + c1 * 8, &Ks[buf ^ 1][ldsOff1]);
                gload16(Vg + (size_t)r0 * 2048 + nkv + c0 * 8, &Vs[buf ^ 1][ldsOff0]);
                gload16(Vg + (size_t)r1 * 2048 + nkv + c1 * 8, &Vs[buf ^ 1][ldsOff1]);
            }

            // ---- QK^T ----
            f32x4 sb[4];
#pragma unroll
            for (int nj = 0; nj < 4; nj++) {
                const int r = nj * 16 + lr;
                short8 kf0 = *(const short8*)&Ks[buf][r * 64 + ((lk    ) ^ (r & 7)) * 8];
                short8 kf1 = *(const short8*)&Ks[buf][r * 64 + ((lk + 4) ^ (r & 7)) * 8];
                f32x4 z = {0.f, 0.f, 0.f, 0.f};
                z = __builtin_amdgcn_mfma_f32_16x16x32_bf16(qf0, kf0, z, 0, 0, 0);
                z = __builtin_amdgcn_mfma_f32_16x16x32_bf16(qf1, kf1, z, 0, 0, 0);
                sb[nj] = z;
            }
            if (kv0 + 63 > q0) {
#pragma unroll
                for (int nj = 0; nj < 4; nj++) {
                    int kv = kv0 + nj * 16 + lr;
#pragma unroll
                    for (int i = 0; i < 4; i++) {
                        int qr = q0 + lk * 4 + i;
                        if (kv > qr) sb[nj][i] = NEGINF;
                    }
                }
            }
            // ---- online softmax (base-2, raw v_exp_f32) ----
            float scale[4];
#pragma unroll
            for (int i = 0; i < 4; i++) {
                float mx = fmaxf(fmaxf(sb[0][i], sb[1][i]), fmaxf(sb[2][i], sb[3][i]));
                mx = fmaxf(mx, __shfl_xor(mx, 1, 16));
                mx = fmaxf(mx, __shfl_xor(mx, 2, 16));
                mx = fmaxf(mx, __shfl_xor(mx, 4, 16));
                mx = fmaxf(mx, __shfl_xor(mx, 8, 16));
                float mnew = fmaxf(mrow[i], mx);
                scale[i] = fast_exp2(mrow[i] - mnew);
                mrow[i] = mnew;
                float psum = 0.f;
#pragma unroll
                for (int nj = 0; nj < 4; nj++) {
                    float p = fast_exp2(sb[nj][i] - mnew);
                    sb[nj][i] = p;
                    psum += p;
                }
                psum += __shfl_xor(psum, 1, 16);
                psum += __shfl_xor(psum, 2, 16);
                psum += __shfl_xor(psum, 4, 16);
                psum += __shfl_xor(psum, 8, 16);
                ssum[i] = ssum[i] * scale[i] + psum;
            }
#pragma unroll
            for (int nj = 0; nj < 4; nj++)
#pragma unroll
                for (int i = 0; i < 4; i++)
                    Plds[wv][lk * 4 + i][nj * 16 + lr] = f2bf(sb[nj][i]);
#pragma unroll
            for (int ni = 0; ni < 4; ni++)
#pragma unroll
                for (int i = 0; i < 4; i++)
                    acc[ni][i] *= scale[i];
            short8 pf0 = *(const short8*)&Plds[wv][lr][lk * 8];
            short8 pf1 = *(const short8*)&Plds[wv][lr][32 + lk * 8];
            // ---- PV ----
#pragma unroll
            for (int ni = 0; ni < 4; ni++) {
                const int r = ni * 16 + lr;
                short8 vf0 = *(const short8*)&Vs[buf][r * 64 + ((lk    ) ^ (r & 7)) * 8];
                short8 vf1 = *(const short8*)&Vs[buf][r * 64 + ((lk + 4) ^ (r & 7)) * 8];
                acc[ni] = __builtin_amdgcn_mfma_f32_16x16x32_bf16(pf0, vf0, acc[ni], 0, 0, 0);
                acc[ni] = __builtin_amdgcn_mfma_f32_16x16x32_bf16(pf1, vf1, acc[ni], 0, 0, 0);
            }

            asm volatile("s_waitcnt vmcnt(0)" ::: "memory");
            __syncthreads();
            buf ^= 1;
        }

#pragma unroll
        for (int ni = 0; ni < 4; ni++) {
#pragma unroll
            for (int i = 0; i < 4; i++) {
                int tq = q0 + lk * 4 + i;
                float val = acc[ni][i] / ssum[i];
                ctx[(size_t)(tq * 2 + bb) * 1024 + h * 64 + ni * 16 + lr] = f2bf(val);
            }
        }
        __syncthreads();
    }
}

extern "C" void kernel_launch(void* const* d_in, const int* in_sizes, int n_in,
                              void* d_out, int out_size, void* d_ws, size_t ws_size,
                              hipStream_t stream) {
    const float* hs     = (const float*)d_in[0];
    const float* proj_w = (const float*)d_in[1];
    const float* proj_b = (const float*)d_in[2];
    const float* out_w  = (const float*)d_in[3];
    const float* out_b  = (const float*)d_in[4];
    const float* rm_i   = (const float*)d_in[5];
    const float* sm_i   = (const float*)d_in[6];
    const float* rm_o   = (const float*)d_in[7];
    const float* sm_o   = (const float*)d_in[8];
    const float* r_i    = (const float*)d_in[9];
    const float* s_i    = (const float*)d_in[10];
    const float* r_o    = (const float*)d_in[11];
    const float* s_o    = (const float*)d_in[12];
    const int*   lang   = (const int*)d_in[13];
    float* out = (float*)d_out;

    char* ws = (char*)d_ws;
    u16* hsb   = (u16*)(ws);
    u16* w_in  = (u16*)(ws + (size_t)(8 << 20));
    u16* w_out = (u16*)(ws + (size_t)(14 << 20));
    u16* qb    = (u16*)(ws + (size_t)(16 << 20));
    u16* kb    = (u16*)(ws + (size_t)(24 << 20));
    u16* vtb   = (u16*)(ws + (size_t)(32 << 20));
    u16* ctxb  = (u16*)(ws + (size_t)(40 << 20));
    u16* vb    = ctxb;  // vb dead before attn writes ctxb — safe overlap

    cast_hidden_kernel<<<dim3(4096), dim3(256), 0, stream>>>(hs, hsb);
    prep_w_kernel<<<dim3(3072), dim3(256), 0, stream>>>(proj_w, rm_i, sm_i, r_i, s_i, lang, w_in, 3072);
    prep_w_kernel<<<dim3(1024), dim3(256), 0, stream>>>(out_w, rm_o, sm_o, r_o, s_o, lang, w_out, 1024);
    gemm_bf16<0><<<dim3(24, 32), dim3(256), 0, stream>>>(hsb, w_in, proj_b, 1024, (float*)nullptr, qb, kb, vb);
    tr_v_kernel<<<dim3(32, 32), dim3(256), 0, stream>>>(vb, vtb);
    attn_kernel<<<dim3(512), dim3(256), 0, stream>>>(qb, kb, vtb, ctxb);
    gemm_bf16<1><<<dim3(8, 32), dim3(256), 0, stream>>>(ctxb, w_out, out_b, 1024, out, (u16*)nullptr, (u16*)nullptr, (u16*)nullptr);
}

// Round 9
// 234.716 us; speedup vs baseline: 1.0977x; 1.0766x over previous
//
#include <hip/hip_runtime.h>
#include <hip/hip_bf16.h>

typedef __attribute__((ext_vector_type(8))) short short8;
typedef __attribute__((ext_vector_type(4))) float f32x4;
typedef unsigned short u16;

#define NEGINF (-1e9f)

__device__ __forceinline__ u16 f2bf(float x) {
    union { float f; unsigned int u; } v; v.f = x;
    unsigned int r = v.u + 0x7fff + ((v.u >> 16) & 1);
    return (u16)(r >> 16);
}

// raw v_exp_f32: D = 2^x, single transcendental instruction
__device__ __forceinline__ float fast_exp2(float x) {
    float r;
    asm volatile("v_exp_f32 %0, %1" : "=v"(r) : "v"(x));
    return r;
}

__device__ __forceinline__ void gload16(const void* g, void* l) {
    __builtin_amdgcn_global_load_lds(
        (const __attribute__((address_space(1))) unsigned int*)g,
        (__attribute__((address_space(3))) unsigned int*)l, 16, 0, 0);
}

// ---------------- cast hidden fp32 -> bf16 ----------------
__global__ __launch_bounds__(256) void cast_hidden_kernel(const float* __restrict__ in,
                                                          u16* __restrict__ out) {
    int idx = (blockIdx.x * 256 + threadIdx.x) * 4;
    float4 v = *(const float4*)&in[idx];
    ushort4 o;
    o.x = f2bf(v.x); o.y = f2bf(v.y); o.z = f2bf(v.z); o.w = f2bf(v.w);
    *(ushort4*)&out[idx] = o;
}

// ---------------- weight prep: w = pw * (rm^T sm) + (r^T s), bf16 out ----------------
__global__ __launch_bounds__(256) void prep_w_kernel(const float* __restrict__ w,
                                                     const float* __restrict__ rm,
                                                     const float* __restrict__ sm,
                                                     const float* __restrict__ ra,
                                                     const float* __restrict__ sa,
                                                     const int* __restrict__ lang,
                                                     u16* __restrict__ out, int rows) {
    const int li = lang[0];
    int idx = blockIdx.x * 256 + threadIdx.x;
    int e = idx >> 8;
    int f = (idx & 255) * 4;
    float4 pw = *(const float4*)&w[(size_t)e * 1024 + f];
    float mul0 = 0.f, mul1 = 0.f, mul2 = 0.f, mul3 = 0.f;
    float add0 = 0.f, add1 = 0.f, add2 = 0.f, add3 = 0.f;
#pragma unroll
    for (int r = 0; r < 4; r++) {
        float a = rm[(size_t)(li * 4 + r) * rows + e];
        float4 b = *(const float4*)&sm[(size_t)(li * 4 + r) * 1024 + f];
        float c = ra[(size_t)(li * 4 + r) * rows + e];
        float4 d = *(const float4*)&sa[(size_t)(li * 4 + r) * 1024 + f];
        mul0 += a * b.x; mul1 += a * b.y; mul2 += a * b.z; mul3 += a * b.w;
        add0 += c * d.x; add1 += c * d.y; add2 += c * d.z; add3 += c * d.w;
    }
    ushort4 o;
    o.x = f2bf(pw.x * mul0 + add0);
    o.y = f2bf(pw.y * mul1 + add1);
    o.z = f2bf(pw.z * mul2 + add2);
    o.w = f2bf(pw.w * mul3 + add3);
    *(ushort4*)&out[(size_t)e * 1024 + f] = o;
}

// ---------------- 128x128 bf16 MFMA GEMM, A:MxK row-major, W:NxK row-major ----------------
// EPI 0: qkv epilogue (q scaled by SCALE*log2e; q,k,v all row-major coalesced).
// EPI 1: fp32 out + bias.
template <int EPI>
__global__ __launch_bounds__(256) void gemm_bf16(const u16* __restrict__ A,
                                                 const u16* __restrict__ W,
                                                 const float* __restrict__ bias,
                                                 int K,
                                                 float* __restrict__ outF,
                                                 u16* __restrict__ qb,
                                                 u16* __restrict__ kb,
                                                 u16* __restrict__ vb) {
    __shared__ __align__(16) u16 As[128 * 32];
    __shared__ __align__(16) u16 Bs[128 * 32];
    const int t = threadIdx.x;
    const int lane = t & 63, wv = t >> 6;
    const int lr = lane & 15, lk = lane >> 4;
    const int wr = wv >> 1, wc = wv & 1;
    const int m0 = blockIdx.y * 128, n0 = blockIdx.x * 128;

    const int rowS = t >> 2, kcS = t & 3;
    const u16* gA0 = A + (size_t)(m0 + rowS) * K + kcS * 8;
    const u16* gA1 = gA0 + (size_t)64 * K;
    const u16* gB0 = W + (size_t)(n0 + rowS) * K + kcS * 8;
    const u16* gB1 = gB0 + (size_t)64 * K;
    char* ldsA0 = (char*)As + wv * 1024;
    char* ldsA1 = (char*)As + 4096 + wv * 1024;
    char* ldsB0 = (char*)Bs + wv * 1024;
    char* ldsB1 = (char*)Bs + 4096 + wv * 1024;

    f32x4 acc[4][4] = {};

    for (int k0 = 0; k0 < K; k0 += 32) {
        gload16(gA0 + k0, ldsA0);
        gload16(gA1 + k0, ldsA1);
        gload16(gB0 + k0, ldsB0);
        gload16(gB1 + k0, ldsB1);
        __syncthreads();
        short8 af[4], bf[4];
#pragma unroll
        for (int mi = 0; mi < 4; mi++)
            af[mi] = *(const short8*)&As[(wr * 64 + mi * 16 + lr) * 32 + lk * 8];
#pragma unroll
        for (int ni = 0; ni < 4; ni++)
            bf[ni] = *(const short8*)&Bs[(wc * 64 + ni * 16 + lr) * 32 + lk * 8];
#pragma unroll
        for (int mi = 0; mi < 4; mi++)
#pragma unroll
            for (int ni = 0; ni < 4; ni++)
                acc[mi][ni] = __builtin_amdgcn_mfma_f32_16x16x32_bf16(af[mi], bf[ni], acc[mi][ni], 0, 0, 0);
        __syncthreads();
    }

#pragma unroll
    for (int mi = 0; mi < 4; mi++) {
#pragma unroll
        for (int ni = 0; ni < 4; ni++) {
            int n = n0 + wc * 64 + ni * 16 + lr;
            float bv = bias[n];
#pragma unroll
            for (int i = 0; i < 4; i++) {
                int m = m0 + wr * 64 + mi * 16 + lk * 4 + i;
                float val = acc[mi][ni][i] + bv;
                if (EPI == 0) {
                    int tt = m >> 1, bb = m & 1;
                    int h = n / 192;
                    int rem = n - h * 192;
                    int s = rem >> 6, d = rem & 63;
                    size_t bh = (size_t)(bb * 16 + h);
                    // q pre-scaled by SCALE*log2(e) so attn can use exp2
                    if (s == 0)      qb[(bh * 2048 + tt) * 64 + d] = f2bf(val * 0.18033688f);
                    else if (s == 1) kb[(bh * 2048 + tt) * 64 + d] = f2bf(val);
                    else             vb[(bh * 2048 + tt) * 64 + d] = f2bf(val);
                } else {
                    outF[(size_t)m * 1024 + n] = val;
                }
            }
        }
    }
}

// ---------------- V transpose: vb (BH,T,64) -> vtb (BH,64,T), coalesced both sides ----
__global__ __launch_bounds__(256) void tr_v_kernel(const u16* __restrict__ vb,
                                                   u16* __restrict__ vtb) {
    __shared__ u16 tile[64][72];
    const int bh = blockIdx.y;
    const int t0 = blockIdx.x * 64;
    const int tid = threadIdx.x;
    const int row = tid >> 3, c8 = (tid & 7) * 8;
#pragma unroll
    for (int p = 0; p < 2; p++) {
        short8 v = *(const short8*)&vb[((size_t)bh * 2048 + t0 + row + p * 32) * 64 + c8];
        *(short8*)&tile[row + p * 32][c8] = v;
    }
    __syncthreads();
    const int d = tid >> 2, tg = (tid & 3) * 16;
    short8 a, b;
#pragma unroll
    for (int j = 0; j < 8; j++) a[j] = tile[tg + j][d];
#pragma unroll
    for (int j = 0; j < 8; j++) b[j] = tile[tg + 8 + j][d];
    *(short8*)&vtb[((size_t)bh * 64 + d) * 2048 + t0 + tg] = a;
    *(short8*)&vtb[((size_t)bh * 64 + d) * 2048 + t0 + tg + 8] = b;
}

// ---------------- causal flash attention (swapped QK^T, lane-local rows) ------------
// q: (BH, T, 64) bf16 scaled by SCALE*log2e; k: (BH, T, 64) bf16; vt: (BH, 64, T) bf16
// ctx out: (T*B, 1024) bf16
// Grid: 512 blocks linear. Block handles strips {pair, 31-pair} of 64 q-rows each.
__global__ __launch_bounds__(256) void attn_kernel(const u16* __restrict__ qb,
                                                   const u16* __restrict__ kb,
                                                   const u16* __restrict__ vtb,
                                                   u16* __restrict__ ctx) {
    __shared__ __align__(16) u16 Ks[2][4096];
    __shared__ __align__(16) u16 Vs[2][4096];
    __shared__ __align__(16) u16 Plds[4][16][72];

    const int t = threadIdx.x;
    const int lane = t & 63, wv = t >> 6;
    const int lr = lane & 15, lk = lane >> 4;

    const int d = blockIdx.x;
    const int bh = (d & 7) * 4 + ((d >> 3) >> 4);
    const int pair = (d >> 3) & 15;

    const u16* Kg = kb + (size_t)bh * 2048 * 64;
    const u16* Vg = vtb + (size_t)bh * 64 * 2048;
    const int bb = bh >> 4, h = bh & 15;

    const int p0 = wv * 64 + lane;
    const int r0 = p0 >> 3, c0 = (p0 & 7) ^ (r0 & 7);
    const int p1 = 256 + p0;
    const int r1 = p1 >> 3, c1 = (p1 & 7) ^ (r1 & 7);
    const int ldsOff0 = (wv * 64) * 8;
    const int ldsOff1 = (256 + wv * 64) * 8;

#pragma unroll 1
    for (int sidx = 0; sidx < 2; sidx++) {
        const int strip = sidx == 0 ? pair : 31 - pair;
        const int q0 = strip * 64 + wv * 16;
        const u16* Qp = qb + ((size_t)bh * 2048 + q0) * 64;
        short8 qf0 = *(const short8*)&Qp[lr * 64 + lk * 8];
        short8 qf1 = *(const short8*)&Qp[lr * 64 + 32 + lk * 8];

        f32x4 acc[4] = {};
        float mrow = -3e38f, ssum = 0.f;   // this lane's q-row = q0 + lr

        const int nt = strip + 1;
        int buf = 0;

        {
            gload16(Kg + (size_t)(0 + r0) * 64 + c0 * 8, &Ks[0][ldsOff0]);
            gload16(Kg + (size_t)(0 + r1) * 64 + c1 * 8, &Ks[0][ldsOff1]);
            gload16(Vg + (size_t)r0 * 2048 + 0 + c0 * 8, &Vs[0][ldsOff0]);
            gload16(Vg + (size_t)r1 * 2048 + 0 + c1 * 8, &Vs[0][ldsOff1]);
        }
        asm volatile("s_waitcnt vmcnt(0)" ::: "memory");
        __syncthreads();

#pragma unroll 1
        for (int tt = 0; tt < nt; tt++) {
            const int kv0 = tt * 64;
            if (tt + 1 < nt) {
                const int nkv = kv0 + 64;
                gload16(Kg + (size_t)(nkv + r0) * 64 + c0 * 8, &Ks[buf ^ 1][ldsOff0]);
                gload16(Kg + (size_t)(nkv + r1) * 64 + c1 * 8, &Ks[buf ^ 1][ldsOff1]);
                gload16(Vg + (size_t)r0 * 2048 + nkv + c0 * 8, &Vs[buf ^ 1][ldsOff0]);
                gload16(Vg + (size_t)r1 * 2048 + nkv + c1 * 8, &Vs[buf ^ 1][ldsOff1]);
            }

            // ---- QK^T, swapped operands: D[kv][q], lane owns q-row lr ----
            f32x4 sb[4];
#pragma unroll
            for (int nj = 0; nj < 4; nj++) {
                const int r = nj * 16 + lr;
                short8 kf0 = *(const short8*)&Ks[buf][r * 64 + ((lk    ) ^ (r & 7)) * 8];
                short8 kf1 = *(const short8*)&Ks[buf][r * 64 + ((lk + 4) ^ (r & 7)) * 8];
                f32x4 z = {0.f, 0.f, 0.f, 0.f};
                z = __builtin_amdgcn_mfma_f32_16x16x32_bf16(kf0, qf0, z, 0, 0, 0);
                z = __builtin_amdgcn_mfma_f32_16x16x32_bf16(kf1, qf1, z, 0, 0, 0);
                sb[nj] = z;   // sb[nj][i] = S[q0+lr][kv0 + nj*16 + lk*4 + i]
            }
            if (kv0 + 63 > q0) {
                const int qr = q0 + lr;
#pragma unroll
                for (int nj = 0; nj < 4; nj++) {
                    const int kvb = kv0 + nj * 16 + lk * 4;
#pragma unroll
                    for (int i = 0; i < 4; i++)
                        if (kvb + i > qr) sb[nj][i] = NEGINF;
                }
            }

            // ---- online softmax (lane-local row; 2+2 shfl) ----
            float pm0 = fmaxf(fmaxf(sb[0][0], sb[0][1]), fmaxf(sb[0][2], sb[0][3]));
            float pm1 = fmaxf(fmaxf(sb[1][0], sb[1][1]), fmaxf(sb[1][2], sb[1][3]));
            float pm2 = fmaxf(fmaxf(sb[2][0], sb[2][1]), fmaxf(sb[2][2], sb[2][3]));
            float pm3 = fmaxf(fmaxf(sb[3][0], sb[3][1]), fmaxf(sb[3][2], sb[3][3]));
            float pmax = fmaxf(fmaxf(pm0, pm1), fmaxf(pm2, pm3));
            pmax = fmaxf(pmax, __shfl_xor(pmax, 16));
            pmax = fmaxf(pmax, __shfl_xor(pmax, 32));
            const float mold = mrow;
            const float mnew = fmaxf(mold, pmax);
            const float scl = fast_exp2(mold - mnew);
            mrow = mnew;
            float psum = 0.f;
#pragma unroll
            for (int nj = 0; nj < 4; nj++)
#pragma unroll
                for (int i = 0; i < 4; i++) {
                    float p = fast_exp2(sb[nj][i] - mnew);
                    sb[nj][i] = p;
                    psum += p;
                }
            psum += __shfl_xor(psum, 16);
            psum += __shfl_xor(psum, 32);
            ssum = ssum * scl + psum;

            // P -> LDS, row = lr, packed 8B stores
#pragma unroll
            for (int nj = 0; nj < 4; nj++) {
                ushort4 pk4;
                pk4.x = f2bf(sb[nj][0]); pk4.y = f2bf(sb[nj][1]);
                pk4.z = f2bf(sb[nj][2]); pk4.w = f2bf(sb[nj][3]);
                *(ushort4*)&Plds[wv][lr][nj * 16 + lk * 4] = pk4;
            }

            // deferred rescale: skip when no row's max grew (exact)
            if (!__all(pmax <= mold)) {
                float s0 = __shfl(scl, lk * 4 + 0);
                float s1 = __shfl(scl, lk * 4 + 1);
                float s2 = __shfl(scl, lk * 4 + 2);
                float s3 = __shfl(scl, lk * 4 + 3);
#pragma unroll
                for (int ni = 0; ni < 4; ni++) {
                    acc[ni][0] *= s0; acc[ni][1] *= s1;
                    acc[ni][2] *= s2; acc[ni][3] *= s3;
                }
            }

            short8 pf0 = *(const short8*)&Plds[wv][lr][lk * 8];
            short8 pf1 = *(const short8*)&Plds[wv][lr][32 + lk * 8];
            // ---- PV ----
#pragma unroll
            for (int ni = 0; ni < 4; ni++) {
                const int r = ni * 16 + lr;
                short8 vf0 = *(const short8*)&Vs[buf][r * 64 + ((lk    ) ^ (r & 7)) * 8];
                short8 vf1 = *(const short8*)&Vs[buf][r * 64 + ((lk + 4) ^ (r & 7)) * 8];
                acc[ni] = __builtin_amdgcn_mfma_f32_16x16x32_bf16(pf0, vf0, acc[ni], 0, 0, 0);
                acc[ni] = __builtin_amdgcn_mfma_f32_16x16x32_bf16(pf1, vf1, acc[ni], 0, 0, 0);
            }

            asm volatile("s_waitcnt vmcnt(0)" ::: "memory");
            __syncthreads();
            buf ^= 1;
        }

        float rs0 = 1.0f / __shfl(ssum, lk * 4 + 0);
        float rs1 = 1.0f / __shfl(ssum, lk * 4 + 1);
        float rs2 = 1.0f / __shfl(ssum, lk * 4 + 2);
        float rs3 = 1.0f / __shfl(ssum, lk * 4 + 3);
#pragma unroll
        for (int ni = 0; ni < 4; ni++) {
            int tq = q0 + lk * 4;
            int col = h * 64 + ni * 16 + lr;
            ctx[(size_t)((tq + 0) * 2 + bb) * 1024 + col] = f2bf(acc[ni][0] * rs0);
            ctx[(size_t)((tq + 1) * 2 + bb) * 1024 + col] = f2bf(acc[ni][1] * rs1);
            ctx[(size_t)((tq + 2) * 2 + bb) * 1024 + col] = f2bf(acc[ni][2] * rs2);
            ctx[(size_t)((tq + 3) * 2 + bb) * 1024 + col] = f2bf(acc[ni][3] * rs3);
        }
        __syncthreads();
    }
}

extern "C" void kernel_launch(void* const* d_in, const int* in_sizes, int n_in,
                              void* d_out, int out_size, void* d_ws, size_t ws_size,
                              hipStream_t stream) {
    const float* hs     = (const float*)d_in[0];
    const float* proj_w = (const float*)d_in[1];
    const float* proj_b = (const float*)d_in[2];
    const float* out_w  = (const float*)d_in[3];
    const float* out_b  = (const float*)d_in[4];
    const float* rm_i   = (const float*)d_in[5];
    const float* sm_i   = (const float*)d_in[6];
    const float* rm_o   = (const float*)d_in[7];
    const float* sm_o   = (const float*)d_in[8];
    const float* r_i    = (const float*)d_in[9];
    const float* s_i    = (const float*)d_in[10];
    const float* r_o    = (const float*)d_in[11];
    const float* s_o    = (const float*)d_in[12];
    const int*   lang   = (const int*)d_in[13];
    float* out = (float*)d_out;

    char* ws = (char*)d_ws;
    u16* hsb   = (u16*)(ws);
    u16* w_in  = (u16*)(ws + (size_t)(8 << 20));
    u16* w_out = (u16*)(ws + (size_t)(14 << 20));
    u16* qb    = (u16*)(ws + (size_t)(16 << 20));
    u16* kb    = (u16*)(ws + (size_t)(24 << 20));
    u16* vtb   = (u16*)(ws + (size_t)(32 << 20));
    u16* ctxb  = (u16*)(ws + (size_t)(40 << 20));
    u16* vb    = ctxb;  // vb dead before attn writes ctxb — safe overlap

    cast_hidden_kernel<<<dim3(4096), dim3(256), 0, stream>>>(hs, hsb);
    prep_w_kernel<<<dim3(3072), dim3(256), 0, stream>>>(proj_w, rm_i, sm_i, r_i, s_i, lang, w_in, 3072);
    prep_w_kernel<<<dim3(1024), dim3(256), 0, stream>>>(out_w, rm_o, sm_o, r_o, s_o, lang, w_out, 1024);
    gemm_bf16<0><<<dim3(24, 32), dim3(256), 0, stream>>>(hsb, w_in, proj_b, 1024, (float*)nullptr, qb, kb, vb);
    tr_v_kernel<<<dim3(32, 32), dim3(256), 0, stream>>>(vb, vtb);
    attn_kernel<<<dim3(512), dim3(256), 0, stream>>>(qb, kb, vtb, ctxb);
    gemm_bf16<1><<<dim3(8, 32), dim3(256), 0, stream>>>(ctxb, w_out, out_b, 1024, out, (u16*)nullptr, (u16*)nullptr, (u16*)nullptr);
}

// Round 10
// 229.420 us; speedup vs baseline: 1.1230x; 1.0231x over previous
//
#include <hip/hip_runtime.h>
#include <hip/hip_bf16.h>

typedef __attribute__((ext_vector_type(8))) short short8;
typedef __attribute__((ext_vector_type(4))) float f32x4;
typedef unsigned short u16;
typedef unsigned int u32;

#define NEGINF (-1e9f)

__device__ __forceinline__ u16 f2bf(float x) {
    union { float f; unsigned int u; } v; v.f = x;
    unsigned int r = v.u + 0x7fff + ((v.u >> 16) & 1);
    return (u16)(r >> 16);
}

// raw v_exp_f32: D = 2^x, single transcendental instruction
__device__ __forceinline__ float fast_exp2(float x) {
    float r;
    asm volatile("v_exp_f32 %0, %1" : "=v"(r) : "v"(x));
    return r;
}

// packed f32x2 -> bf16x2 (RNE), D.lo = bf16(a), D.hi = bf16(b)
__device__ __forceinline__ u32 cvt_pk_bf16(float a, float b) {
    u32 r;
    asm("v_cvt_pk_bf16_f32 %0, %1, %2" : "=v"(r) : "v"(a), "v"(b));
    return r;
}

__device__ __forceinline__ void gload16(const void* g, void* l) {
    __builtin_amdgcn_global_load_lds(
        (const __attribute__((address_space(1))) unsigned int*)g,
        (__attribute__((address_space(3))) unsigned int*)l, 16, 0, 0);
}

// ---------------- cast hidden fp32 -> bf16 ----------------
__global__ __launch_bounds__(256) void cast_hidden_kernel(const float* __restrict__ in,
                                                          u16* __restrict__ out) {
    int idx = (blockIdx.x * 256 + threadIdx.x) * 4;
    float4 v = *(const float4*)&in[idx];
    ushort4 o;
    o.x = f2bf(v.x); o.y = f2bf(v.y); o.z = f2bf(v.z); o.w = f2bf(v.w);
    *(ushort4*)&out[idx] = o;
}

// ---------------- weight prep: w = pw * (rm^T sm) + (r^T s), bf16 out ----------------
__global__ __launch_bounds__(256) void prep_w_kernel(const float* __restrict__ w,
                                                     const float* __restrict__ rm,
                                                     const float* __restrict__ sm,
                                                     const float* __restrict__ ra,
                                                     const float* __restrict__ sa,
                                                     const int* __restrict__ lang,
                                                     u16* __restrict__ out, int rows) {
    const int li = lang[0];
    int idx = blockIdx.x * 256 + threadIdx.x;
    int e = idx >> 8;
    int f = (idx & 255) * 4;
    float4 pw = *(const float4*)&w[(size_t)e * 1024 + f];
    float mul0 = 0.f, mul1 = 0.f, mul2 = 0.f, mul3 = 0.f;
    float add0 = 0.f, add1 = 0.f, add2 = 0.f, add3 = 0.f;
#pragma unroll
    for (int r = 0; r < 4; r++) {
        float a = rm[(size_t)(li * 4 + r) * rows + e];
        float4 b = *(const float4*)&sm[(size_t)(li * 4 + r) * 1024 + f];
        float c = ra[(size_t)(li * 4 + r) * rows + e];
        float4 d = *(const float4*)&sa[(size_t)(li * 4 + r) * 1024 + f];
        mul0 += a * b.x; mul1 += a * b.y; mul2 += a * b.z; mul3 += a * b.w;
        add0 += c * d.x; add1 += c * d.y; add2 += c * d.z; add3 += c * d.w;
    }
    ushort4 o;
    o.x = f2bf(pw.x * mul0 + add0);
    o.y = f2bf(pw.y * mul1 + add1);
    o.z = f2bf(pw.z * mul2 + add2);
    o.w = f2bf(pw.w * mul3 + add3);
    *(ushort4*)&out[(size_t)e * 1024 + f] = o;
}

// ---------------- 128x128 bf16 MFMA GEMM (QKV), A:MxK row-major, W:NxK row-major -------
__global__ __launch_bounds__(256) void gemm_qkv(const u16* __restrict__ A,
                                                const u16* __restrict__ W,
                                                const float* __restrict__ bias,
                                                int K,
                                                u16* __restrict__ qb,
                                                u16* __restrict__ kb,
                                                u16* __restrict__ vb) {
    __shared__ __align__(16) u16 As[128 * 32];
    __shared__ __align__(16) u16 Bs[128 * 32];
    const int t = threadIdx.x;
    const int lane = t & 63, wv = t >> 6;
    const int lr = lane & 15, lk = lane >> 4;
    const int wr = wv >> 1, wc = wv & 1;
    const int m0 = blockIdx.y * 128, n0 = blockIdx.x * 128;

    const int rowS = t >> 2, kcS = t & 3;
    const u16* gA0 = A + (size_t)(m0 + rowS) * K + kcS * 8;
    const u16* gA1 = gA0 + (size_t)64 * K;
    const u16* gB0 = W + (size_t)(n0 + rowS) * K + kcS * 8;
    const u16* gB1 = gB0 + (size_t)64 * K;
    char* ldsA0 = (char*)As + wv * 1024;
    char* ldsA1 = (char*)As + 4096 + wv * 1024;
    char* ldsB0 = (char*)Bs + wv * 1024;
    char* ldsB1 = (char*)Bs + 4096 + wv * 1024;

    f32x4 acc[4][4] = {};

    for (int k0 = 0; k0 < K; k0 += 32) {
        gload16(gA0 + k0, ldsA0);
        gload16(gA1 + k0, ldsA1);
        gload16(gB0 + k0, ldsB0);
        gload16(gB1 + k0, ldsB1);
        __syncthreads();
        short8 af[4], bf[4];
#pragma unroll
        for (int mi = 0; mi < 4; mi++)
            af[mi] = *(const short8*)&As[(wr * 64 + mi * 16 + lr) * 32 + lk * 8];
#pragma unroll
        for (int ni = 0; ni < 4; ni++)
            bf[ni] = *(const short8*)&Bs[(wc * 64 + ni * 16 + lr) * 32 + lk * 8];
#pragma unroll
        for (int mi = 0; mi < 4; mi++)
#pragma unroll
            for (int ni = 0; ni < 4; ni++)
                acc[mi][ni] = __builtin_amdgcn_mfma_f32_16x16x32_bf16(af[mi], bf[ni], acc[mi][ni], 0, 0, 0);
        __syncthreads();
    }

#pragma unroll
    for (int mi = 0; mi < 4; mi++) {
#pragma unroll
        for (int ni = 0; ni < 4; ni++) {
            int n = n0 + wc * 64 + ni * 16 + lr;
            float bv = bias[n];
#pragma unroll
            for (int i = 0; i < 4; i++) {
                int m = m0 + wr * 64 + mi * 16 + lk * 4 + i;
                float val = acc[mi][ni][i] + bv;
                int tt = m >> 1, bb = m & 1;
                int h = n / 192;
                int rem = n - h * 192;
                int s = rem >> 6, d = rem & 63;
                size_t bh = (size_t)(bb * 16 + h);
                // q pre-scaled by SCALE*log2(e) so attn can use exp2
                if (s == 0)      qb[(bh * 2048 + tt) * 64 + d] = f2bf(val * 0.18033688f);
                else if (s == 1) kb[(bh * 2048 + tt) * 64 + d] = f2bf(val);
                else             vb[(bh * 2048 + tt) * 64 + d] = f2bf(val);
            }
        }
    }
}

// ---------------- out-proj GEMM: 128x64 tile, 512 blocks (2/CU) ----------------------
// A: (4096,1024) bf16 row-major; W: (1024,1024) bf16 NxK; out fp32 + bias.
__global__ __launch_bounds__(256) void gemm_out(const u16* __restrict__ A,
                                                const u16* __restrict__ W,
                                                const float* __restrict__ bias,
                                                float* __restrict__ outF) {
    __shared__ __align__(16) u16 As[128 * 32];
    __shared__ __align__(16) u16 Bs[64 * 32];
    const int K = 1024;
    const int t = threadIdx.x;
    const int lane = t & 63, wv = t >> 6;
    const int lr = lane & 15, lk = lane >> 4;
    const int wr = wv >> 1, wc = wv & 1;   // wr: 2x64 rows, wc: 2x32 cols
    const int m0 = blockIdx.y * 128, n0 = blockIdx.x * 64;

    const int rowS = t >> 2, kcS = t & 3;
    const u16* gA0 = A + (size_t)(m0 + rowS) * K + kcS * 8;
    const u16* gA1 = gA0 + (size_t)64 * K;
    const u16* gB0 = W + (size_t)(n0 + rowS) * K + kcS * 8;   // rows 0..63
    char* ldsA0 = (char*)As + wv * 1024;
    char* ldsA1 = (char*)As + 4096 + wv * 1024;
    char* ldsB0 = (char*)Bs + wv * 1024;

    f32x4 acc[4][2] = {};

    for (int k0 = 0; k0 < K; k0 += 32) {
        gload16(gA0 + k0, ldsA0);
        gload16(gA1 + k0, ldsA1);
        gload16(gB0 + k0, ldsB0);
        __syncthreads();
        short8 af[4], bf[2];
#pragma unroll
        for (int mi = 0; mi < 4; mi++)
            af[mi] = *(const short8*)&As[(wr * 64 + mi * 16 + lr) * 32 + lk * 8];
#pragma unroll
        for (int ni = 0; ni < 2; ni++)
            bf[ni] = *(const short8*)&Bs[(wc * 32 + ni * 16 + lr) * 32 + lk * 8];
#pragma unroll
        for (int mi = 0; mi < 4; mi++)
#pragma unroll
            for (int ni = 0; ni < 2; ni++)
                acc[mi][ni] = __builtin_amdgcn_mfma_f32_16x16x32_bf16(af[mi], bf[ni], acc[mi][ni], 0, 0, 0);
        __syncthreads();
    }

#pragma unroll
    for (int mi = 0; mi < 4; mi++) {
#pragma unroll
        for (int ni = 0; ni < 2; ni++) {
            int n = n0 + wc * 32 + ni * 16 + lr;
            float bv = bias[n];
#pragma unroll
            for (int i = 0; i < 4; i++) {
                int m = m0 + wr * 64 + mi * 16 + lk * 4 + i;
                outF[(size_t)m * 1024 + n] = acc[mi][ni][i] + bv;
            }
        }
    }
}

// ---------------- V transpose: vb (BH,T,64) -> vtb (BH,64,T), coalesced both sides ----
__global__ __launch_bounds__(256) void tr_v_kernel(const u16* __restrict__ vb,
                                                   u16* __restrict__ vtb) {
    __shared__ u16 tile[64][72];
    const int bh = blockIdx.y;
    const int t0 = blockIdx.x * 64;
    const int tid = threadIdx.x;
    const int row = tid >> 3, c8 = (tid & 7) * 8;
#pragma unroll
    for (int p = 0; p < 2; p++) {
        short8 v = *(const short8*)&vb[((size_t)bh * 2048 + t0 + row + p * 32) * 64 + c8];
        *(short8*)&tile[row + p * 32][c8] = v;
    }
    __syncthreads();
    const int d = tid >> 2, tg = (tid & 3) * 16;
    short8 a, b;
#pragma unroll
    for (int j = 0; j < 8; j++) a[j] = tile[tg + j][d];
#pragma unroll
    for (int j = 0; j < 8; j++) b[j] = tile[tg + 8 + j][d];
    *(short8*)&vtb[((size_t)bh * 64 + d) * 2048 + t0 + tg] = a;
    *(short8*)&vtb[((size_t)bh * 64 + d) * 2048 + t0 + tg + 8] = b;
}

// ---------------- causal flash attention (swapped QK^T, in-register P) ---------------
// q: (BH, T, 64) bf16 scaled by SCALE*log2e; k: (BH, T, 64) bf16; vt: (BH, 64, T) bf16
// ctx out: (T*B, 1024) bf16
// Grid: 512 blocks linear. Block handles strips {pair, 31-pair} of 64 q-rows each.
__global__ __launch_bounds__(256) void attn_kernel(const u16* __restrict__ qb,
                                                   const u16* __restrict__ kb,
                                                   const u16* __restrict__ vtb,
                                                   u16* __restrict__ ctx) {
    __shared__ __align__(16) u16 Ks[2][4096];
    __shared__ __align__(16) u16 Vs[2][4096];

    const int t = threadIdx.x;
    const int lane = t & 63, wv = t >> 6;
    const int lr = lane & 15, lk = lane >> 4;
    const int b4 = lk & 1, bx = (lk & 1) ^ (lk >> 1);

    const int d = blockIdx.x;
    const int bh = (d & 7) * 4 + ((d >> 3) >> 4);
    const int pair = (d >> 3) & 15;

    const u16* Kg = kb + (size_t)bh * 2048 * 64;
    const u16* Vg = vtb + (size_t)bh * 64 * 2048;
    const int bb = bh >> 4, h = bh & 15;

    const int p0 = wv * 64 + lane;
    const int r0 = p0 >> 3, c0 = (p0 & 7) ^ (r0 & 7);
    const int p1 = 256 + p0;
    const int r1 = p1 >> 3, c1 = (p1 & 7) ^ (r1 & 7);
    const int ldsOff0 = (wv * 64) * 8;
    const int ldsOff1 = (256 + wv * 64) * 8;

#pragma unroll 1
    for (int sidx = 0; sidx < 2; sidx++) {
        const int strip = sidx == 0 ? pair : 31 - pair;
        const int q0 = strip * 64 + wv * 16;
        const u16* Qp = qb + ((size_t)bh * 2048 + q0) * 64;
        short8 qf0 = *(const short8*)&Qp[lr * 64 + lk * 8];
        short8 qf1 = *(const short8*)&Qp[lr * 64 + 32 + lk * 8];

        f32x4 acc[4] = {};
        float mrow = -3e38f, ssum = 0.f;   // this lane's q-row = q0 + lr

        const int nt = strip + 1;
        int buf = 0;

        {
            gload16(Kg + (size_t)(0 + r0) * 64 + c0 * 8, &Ks[0][ldsOff0]);
            gload16(Kg + (size_t)(0 + r1) * 64 + c1 * 8, &Ks[0][ldsOff1]);
            gload16(Vg + (size_t)r0 * 2048 + 0 + c0 * 8, &Vs[0][ldsOff0]);
            gload16(Vg + (size_t)r1 * 2048 + 0 + c1 * 8, &Vs[0][ldsOff1]);
        }
        asm volatile("s_waitcnt vmcnt(0)" ::: "memory");
        __syncthreads();

#pragma unroll 1
        for (int tt = 0; tt < nt; tt++) {
            const int kv0 = tt * 64;
            if (tt + 1 < nt) {
                const int nkv = kv0 + 64;
                gload16(Kg + (size_t)(nkv + r0) * 64 + c0 * 8, &Ks[buf ^ 1][ldsOff0]);
                gload16(Kg + (size_t)(nkv + r1) * 64 + c1 * 8, &Ks[buf ^ 1][ldsOff1]);
                gload16(Vg + (size_t)r0 * 2048 + nkv + c0 * 8, &Vs[buf ^ 1][ldsOff0]);
                gload16(Vg + (size_t)r1 * 2048 + nkv + c1 * 8, &Vs[buf ^ 1][ldsOff1]);
            }

            // ---- QK^T, swapped operands: lane owns q-row lr ----
            f32x4 sb[4];
#pragma unroll
            for (int nj = 0; nj < 4; nj++) {
                const int r = nj * 16 + lr;
                short8 kf0 = *(const short8*)&Ks[buf][r * 64 + ((lk    ) ^ (r & 7)) * 8];
                short8 kf1 = *(const short8*)&Ks[buf][r * 64 + ((lk + 4) ^ (r & 7)) * 8];
                f32x4 z = {0.f, 0.f, 0.f, 0.f};
                z = __builtin_amdgcn_mfma_f32_16x16x32_bf16(kf0, qf0, z, 0, 0, 0);
                z = __builtin_amdgcn_mfma_f32_16x16x32_bf16(kf1, qf1, z, 0, 0, 0);
                sb[nj] = z;   // sb[nj][i] = S[q0+lr][kv0 + nj*16 + lk*4 + i]
            }
            if (kv0 + 63 > q0) {
                const int qr = q0 + lr;
#pragma unroll
                for (int nj = 0; nj < 4; nj++) {
                    const int kvb = kv0 + nj * 16 + lk * 4;
#pragma unroll
                    for (int i = 0; i < 4; i++)
                        if (kvb + i > qr) sb[nj][i] = NEGINF;
                }
            }

            // ---- online softmax (lane-local row; 2+2 shfl) ----
            float pm0 = fmaxf(fmaxf(sb[0][0], sb[0][1]), fmaxf(sb[0][2], sb[0][3]));
            float pm1 = fmaxf(fmaxf(sb[1][0], sb[1][1]), fmaxf(sb[1][2], sb[1][3]));
            float pm2 = fmaxf(fmaxf(sb[2][0], sb[2][1]), fmaxf(sb[2][2], sb[2][3]));
            float pm3 = fmaxf(fmaxf(sb[3][0], sb[3][1]), fmaxf(sb[3][2], sb[3][3]));
            float pmax = fmaxf(fmaxf(pm0, pm1), fmaxf(pm2, pm3));
            pmax = fmaxf(pmax, __shfl_xor(pmax, 16));
            pmax = fmaxf(pmax, __shfl_xor(pmax, 32));
            const float mold = mrow;
            const float mnew = fmaxf(mold, pmax);
            const float scl = fast_exp2(mold - mnew);
            mrow = mnew;
            float psum = 0.f;
#pragma unroll
            for (int nj = 0; nj < 4; nj++)
#pragma unroll
                for (int i = 0; i < 4; i++) {
                    float p = fast_exp2(sb[nj][i] - mnew);
                    sb[nj][i] = p;
                    psum += p;
                }
            psum += __shfl_xor(psum, 16);
            psum += __shfl_xor(psum, 32);
            ssum = ssum * scl + psum;

            // ---- P -> A-fragment in registers: cvt_pk + 2-stage butterfly ----
            // e[nj][c] covers kv = nj*16 + lk*4 + 2c + {0,1}
            u32 e00 = cvt_pk_bf16(sb[0][0], sb[0][1]);
            u32 e01 = cvt_pk_bf16(sb[0][2], sb[0][3]);
            u32 e10 = cvt_pk_bf16(sb[1][0], sb[1][1]);
            u32 e11 = cvt_pk_bf16(sb[1][2], sb[1][3]);
            u32 e20 = cvt_pk_bf16(sb[2][0], sb[2][1]);
            u32 e21 = cvt_pk_bf16(sb[2][2], sb[2][3]);
            u32 e30 = cvt_pk_bf16(sb[3][0], sb[3][1]);
            u32 e31 = cvt_pk_bf16(sb[3][2], sb[3][3]);
            // stage A: exchange with lane^16 (b4 flip)
            u32 s0 = b4 ? e00 : e10, s1 = b4 ? e01 : e11;
            u32 s2 = b4 ? e20 : e30, s3 = b4 ? e21 : e31;
            u32 ra0 = __shfl_xor((int)s0, 16), ra1 = __shfl_xor((int)s1, 16);
            u32 ra2 = __shfl_xor((int)s2, 16), ra3 = __shfl_xor((int)s3, 16);
            u32 kA0 = b4 ? e10 : e00, kA1 = b4 ? e11 : e01;
            u32 kA2 = b4 ? e30 : e20, kA3 = b4 ? e31 : e21;
            u32 g0 = b4 ? ra0 : kA0, g1 = b4 ? ra1 : kA1;
            u32 g2 = b4 ? kA0 : ra0, g3 = b4 ? kA1 : ra1;
            u32 g4 = b4 ? ra2 : kA2, g5 = b4 ? ra3 : kA3;
            u32 g6 = b4 ? kA2 : ra2, g7 = b4 ? kA3 : ra3;
            // stage B: lanes with b4^b5 swap with lane^48
            u32 h0 = __shfl_xor((int)g0, 48), h1 = __shfl_xor((int)g1, 48);
            u32 h2 = __shfl_xor((int)g2, 48), h3 = __shfl_xor((int)g3, 48);
            u32 h4 = __shfl_xor((int)g4, 48), h5 = __shfl_xor((int)g5, 48);
            u32 h6 = __shfl_xor((int)g6, 48), h7 = __shfl_xor((int)g7, 48);
            union { u32 u[4]; short8 s; } P0, P1;
            P0.u[0] = bx ? h0 : g0; P0.u[1] = bx ? h1 : g1;
            P0.u[2] = bx ? h2 : g2; P0.u[3] = bx ? h3 : g3;
            P1.u[0] = bx ? h4 : g4; P1.u[1] = bx ? h5 : g5;
            P1.u[2] = bx ? h6 : g6; P1.u[3] = bx ? h7 : g7;

            // deferred rescale: skip when no row's max grew (exact)
            if (!__all(pmax <= mold)) {
                float t0s = __shfl(scl, lk * 4 + 0);
                float t1s = __shfl(scl, lk * 4 + 1);
                float t2s = __shfl(scl, lk * 4 + 2);
                float t3s = __shfl(scl, lk * 4 + 3);
#pragma unroll
                for (int ni = 0; ni < 4; ni++) {
                    acc[ni][0] *= t0s; acc[ni][1] *= t1s;
                    acc[ni][2] *= t2s; acc[ni][3] *= t3s;
                }
            }

            // ---- PV ----
#pragma unroll
            for (int ni = 0; ni < 4; ni++) {
                const int r = ni * 16 + lr;
                short8 vf0 = *(const short8*)&Vs[buf][r * 64 + ((lk    ) ^ (r & 7)) * 8];
                short8 vf1 = *(const short8*)&Vs[buf][r * 64 + ((lk + 4) ^ (r & 7)) * 8];
                acc[ni] = __builtin_amdgcn_mfma_f32_16x16x32_bf16(P0.s, vf0, acc[ni], 0, 0, 0);
                acc[ni] = __builtin_amdgcn_mfma_f32_16x16x32_bf16(P1.s, vf1, acc[ni], 0, 0, 0);
            }

            asm volatile("s_waitcnt vmcnt(0)" ::: "memory");
            __syncthreads();
            buf ^= 1;
        }

        float rs0 = 1.0f / __shfl(ssum, lk * 4 + 0);
        float rs1 = 1.0f / __shfl(ssum, lk * 4 + 1);
        float rs2 = 1.0f / __shfl(ssum, lk * 4 + 2);
        float rs3 = 1.0f / __shfl(ssum, lk * 4 + 3);
#pragma unroll
        for (int ni = 0; ni < 4; ni++) {
            int tq = q0 + lk * 4;
            int col = h * 64 + ni * 16 + lr;
            ctx[(size_t)((tq + 0) * 2 + bb) * 1024 + col] = f2bf(acc[ni][0] * rs0);
            ctx[(size_t)((tq + 1) * 2 + bb) * 1024 + col] = f2bf(acc[ni][1] * rs1);
            ctx[(size_t)((tq + 2) * 2 + bb) * 1024 + col] = f2bf(acc[ni][2] * rs2);
            ctx[(size_t)((tq + 3) * 2 + bb) * 1024 + col] = f2bf(acc[ni][3] * rs3);
        }
        __syncthreads();
    }
}

extern "C" void kernel_launch(void* const* d_in, const int* in_sizes, int n_in,
                              void* d_out, int out_size, void* d_ws, size_t ws_size,
                              hipStream_t stream) {
    const float* hs     = (const float*)d_in[0];
    const float* proj_w = (const float*)d_in[1];
    const float* proj_b = (const float*)d_in[2];
    const float* out_w  = (const float*)d_in[3];
    const float* out_b  = (const float*)d_in[4];
    const float* rm_i   = (const float*)d_in[5];
    const float* sm_i   = (const float*)d_in[6];
    const float* rm_o   = (const float*)d_in[7];
    const float* sm_o   = (const float*)d_in[8];
    const float* r_i    = (const float*)d_in[9];
    const float* s_i    = (const float*)d_in[10];
    const float* r_o    = (const float*)d_in[11];
    const float* s_o    = (const float*)d_in[12];
    const int*   lang   = (const int*)d_in[13];
    float* out = (float*)d_out;

    char* ws = (char*)d_ws;
    u16* hsb   = (u16*)(ws);
    u16* w_in  = (u16*)(ws + (size_t)(8 << 20));
    u16* w_out = (u16*)(ws + (size_t)(14 << 20));
    u16* qb    = (u16*)(ws + (size_t)(16 << 20));
    u16* kb    = (u16*)(ws + (size_t)(24 << 20));
    u16* vtb   = (u16*)(ws + (size_t)(32 << 20));
    u16* ctxb  = (u16*)(ws + (size_t)(40 << 20));
    u16* vb    = ctxb;  // vb dead before attn writes ctxb — safe overlap

    cast_hidden_kernel<<<dim3(4096), dim3(256), 0, stream>>>(hs, hsb);
    prep_w_kernel<<<dim3(3072), dim3(256), 0, stream>>>(proj_w, rm_i, sm_i, r_i, s_i, lang, w_in, 3072);
    prep_w_kernel<<<dim3(1024), dim3(256), 0, stream>>>(out_w, rm_o, sm_o, r_o, s_o, lang, w_out, 1024);
    gemm_qkv<<<dim3(24, 32), dim3(256), 0, stream>>>(hsb, w_in, proj_b, 1024, qb, kb, vb);
    tr_v_kernel<<<dim3(32, 32), dim3(256), 0, stream>>>(vb, vtb);
    attn_kernel<<<dim3(512), dim3(256), 0, stream>>>(qb, kb, vtb, ctxb);
    gemm_out<<<dim3(16, 32), dim3(256), 0, stream>>>(ctxb, w_out, out_b, out);
}